// Round 11
// baseline (105.780 us; speedup 1.0000x reference)
//
#include <hip/hip_runtime.h>
#include <stdint.h>
#include <math.h>

#define CC 22
#define START_I 20
#define STOP_I 21
#define BB 64
#define LL 512
#define DD 512
#define NEGV -100000.0f
#define NCH 32
#define CS 16
#define EROWS 16  // rows per k_emit block

// ws layout
#define EMIT_FLOATS ((BB * LL + CS) * CC)                // + CS rows slack
#define BP_OFF (((EMIT_FLOATS * 4) + 255) & ~255)
#define BP_BYTES (BB * LL * CC)
#define META_OFF ((BP_OFF + BP_BYTES + 255) & ~255)
#define PV_OFF (META_OFF + 1024)                         // 64*32*22 floats = 180224 B
#define PHI_OFF (PV_OFF + BB * NCH * CC * 4)             // 64*32*22*22 floats = 3.96 MB

// ---------------- emissions GEMM: emit[row][c] = x[row]·W[c] + b[c] ----------------
// LDS-tiled: stage x(16x512, stride 516) + W(22x512, stride 516) with coalesced
// float4 loads; 352 threads each compute one (row, class) dot from LDS.
// Per-output k-ascending x/y/z/w order: bit-identical to prior rounds.
__global__ __launch_bounds__(384) void k_emit(const float* __restrict__ x,
                                              const float* __restrict__ W,
                                              const float* __restrict__ bias,
                                              float* __restrict__ emit) {
  __shared__ float xl[EROWS * 516];  // 33,024 B
  __shared__ float Wl[CC * 516];     // 45,408 B  (total 78.4 KB -> 2 blocks/CU)
  const int tid = threadIdx.x;
  const size_t rowbase = (size_t)blockIdx.x * EROWS;
  // stage W: 2816 float4, coalesced
#pragma unroll
  for (int it = 0; it < 8; ++it) {
    int g = it * 384 + tid;
    if (g < CC * (DD / 4)) {
      int c = g >> 7, d4 = g & 127;
      *(float4*)(Wl + c * 516 + 4 * d4) = ((const float4*)W)[g];
    }
  }
  // stage x tile: 2048 float4, coalesced
  const float4* xsrc = (const float4*)(x + rowbase * DD);
#pragma unroll
  for (int it = 0; it < 6; ++it) {
    int g = it * 384 + tid;
    if (g < EROWS * (DD / 4)) {
      int r = g >> 7, d4 = g & 127;
      *(float4*)(xl + r * 516 + 4 * d4) = xsrc[g];
    }
  }
  __syncthreads();
  if (tid < EROWS * CC) {
    const int r = tid / CC, c = tid % CC;
    const float4* xr = (const float4*)(xl + r * 516);
    const float4* wr = (const float4*)(Wl + c * 516);
    float acc = 0.f;
#pragma unroll 8
    for (int i = 0; i < DD / 4; ++i) {
      float4 a = xr[i];
      float4 w = wr[i];
      acc += a.x * w.x + a.y * w.y + a.z * w.z + a.w * w.w;
    }
    emit[(rowbase + r) * CC + c] = acc + bias[c];
  }
}

__device__ __forceinline__ float rlf(float v, int l) {
  return __int_as_float(__builtin_amdgcn_readlane(__float_as_int(v), l));
}

// ---------------- segment transfer matrices (parallel-in-time Viterbi) ----------
__global__ __launch_bounds__(256) void k_seg(const float* __restrict__ emit,
                                             const float* __restrict__ mask,
                                             const float* __restrict__ trans,
                                             float* __restrict__ phi) {
  __shared__ float Ph[2][CC][23];
  __shared__ float els[CS * CC];
  const int seg = blockIdx.x, b = blockIdx.y;
  const int tid = threadIdx.x;
  const int lane = tid & 63;
  int n = 0;  // each wave computes redundantly (no sync needed)
#pragma unroll
  for (int k = 0; k < 8; ++k)
    n += __popcll(__ballot(mask[(size_t)b * LL + k * 64 + lane] > 0.0f));
  const int t0 = seg * CS;
  for (int i = tid; i < CS * CC; i += 256)  // full 352-entry fill
    els[i] = emit[((size_t)b * LL + t0) * CC + i];
  const bool own = tid < 242;
  const int to2 = own ? tid / CC : 0;   // 0..10
  const int frm0 = own ? tid % CC : 0;  // 0..21
  float T0[CC], T1[CC];
  if (own) {
#pragma unroll
    for (int f = 0; f < CC; ++f) {
      T0[f] = trans[to2 * CC + f];
      T1[f] = trans[(to2 + 11) * CC + f];
    }
    Ph[0][to2][frm0] = (to2 == frm0) ? 0.0f : -INFINITY;
    Ph[0][to2 + 11][frm0] = (to2 + 11 == frm0) ? 0.0f : -INFINITY;
  }
  __syncthreads();
  int steps = n - t0;
  steps = steps < 0 ? 0 : (steps > CS ? CS : steps);
  int c = 0;
  for (int q = 0; q < steps; ++q) {  // block-uniform trip count
    if (own) {
      float a0 = -INFINITY, a1 = -INFINITY;
#pragma unroll
      for (int f = 0; f < CC; ++f) {
        float v = Ph[c][f][frm0];
        a0 = fmaxf(a0, v + T0[f]);
        a1 = fmaxf(a1, v + T1[f]);
      }
      Ph[c ^ 1][to2][frm0] = a0 + els[q * CC + to2];
      Ph[c ^ 1][to2 + 11][frm0] = a1 + els[q * CC + to2 + 11];
    }
    __syncthreads();
    c ^= 1;
  }
  if (own) {
    float* pb = phi + ((size_t)b * NCH + seg) * CC * CC;
    pb[to2 * CC + frm0] = Ph[c][to2][frm0];
    pb[(to2 + 11) * CC + frm0] = Ph[c][to2 + 11][frm0];
  }
}

// ---------------- compose: 32 matrix-vector max-plus steps per batch ----------
__global__ __launch_bounds__(64) void k_cmp(const float* __restrict__ phi,
                                            const float* __restrict__ mask,
                                            const float* __restrict__ trans,
                                            float* __restrict__ out_score,
                                            float* __restrict__ pv,
                                            int* __restrict__ meta) {
  const int b = blockIdx.x;
  const int lane = threadIdx.x;
  const int lc = lane < CC ? lane : CC - 1;
  const float Tstop = trans[STOP_I * CC + lc];
  int n = 0;
#pragma unroll
  for (int k = 0; k < 8; ++k)
    n += __popcll(__ballot(mask[(size_t)b * LL + k * 64 + lane] > 0.0f));

  float st = (lane == START_I) ? 0.0f : NEGV;
  const float* pb = phi + (size_t)b * NCH * CC * CC;
  float row[CC], nrow[CC];
#pragma unroll
  for (int f = 0; f < CC; ++f) row[f] = pb[lc * CC + f];
  for (int s = 0; s < NCH; ++s) {
    if (lane < CC) pv[((size_t)b * NCH + s) * CC + lane] = st;
    if (s + 1 < NCH) {
#pragma unroll
      for (int f = 0; f < CC; ++f) nrow[f] = pb[((s + 1) * CC + lc) * CC + f];
    }
    float a = -INFINITY;
#pragma unroll
    for (int f = 0; f < CC; ++f) a = fmaxf(a, row[f] + rlf(st, f));
    st = a;  // identity segments preserve st exactly
#pragma unroll
    for (int f = 0; f < CC; ++f) row[f] = nrow[f];
  }

  float fin = st + Tstop;
  if (lane < CC) out_score[b * CC + lane] = fin;
  float bv = -3.0e38f;
  int bt = 0;
#pragma unroll
  for (int k = 0; k < CC; ++k) {
    float v = rlf(fin, k);
    bool g = v > bv;
    bv = g ? v : bv;
    bt = g ? k : bt;
  }
  if (lane == 0) { meta[b] = n; meta[BB + b] = bt; }
}

// ---------------- parallel replay: backpointers from checkpoints ----------------
__global__ __launch_bounds__(64) void k_rep(const float* __restrict__ emit,
                                            const float* __restrict__ trans,
                                            const float* __restrict__ pv,
                                            const int* __restrict__ meta,
                                            unsigned char* __restrict__ bp) {
  const int c = blockIdx.x, b = blockIdx.y;
  const int lane = threadIdx.x;
  const int n = meta[b];
  const int t0 = c * CS;
  if (t0 >= n) return;
  const int lc = lane < CC ? lane : CC - 1;
  float Trow[CC];
#pragma unroll
  for (int j = 0; j < CC; ++j) Trow[j] = trans[lc * CC + j];
  float st = pv[((size_t)b * NCH + c) * CC + lc];
  const float* eb = emit + (size_t)b * LL * CC;
  float ev[CS];
#pragma unroll
  for (int q = 0; q < CS; ++q) {
    ev[q] = eb[(t0 + q) * CC + lc];
    asm volatile("" : "+v"(ev[q]));
  }
  unsigned char* bpb = bp + (size_t)b * LL * CC;
  const int m = (n - t0) < CS ? (n - t0) : CS;
#pragma unroll
  for (int q = 0; q < CS; ++q) {
    if (q < m) {
      float cand[CC];
#pragma unroll
      for (int j = 0; j < CC; ++j) cand[j] = rlf(st, j) + Trow[j];
      float m0 = fmaxf(fmaxf(cand[0], cand[1]), cand[2]);
      float m1 = fmaxf(fmaxf(cand[3], cand[4]), cand[5]);
      float m2 = fmaxf(fmaxf(cand[6], cand[7]), cand[8]);
      float m3 = fmaxf(fmaxf(cand[9], cand[10]), cand[11]);
      float m4 = fmaxf(fmaxf(cand[12], cand[13]), cand[14]);
      float m5 = fmaxf(fmaxf(cand[15], cand[16]), cand[17]);
      float m6 = fmaxf(fmaxf(cand[18], cand[19]), cand[20]);
      float n0 = fmaxf(fmaxf(m0, m1), m2);
      float n1 = fmaxf(fmaxf(m3, m4), m5);
      float n2 = fmaxf(m6, cand[21]);
      float mx = fmaxf(fmaxf(n0, n1), n2);
      unsigned u = 0;
#pragma unroll
      for (int j = 0; j < CC; ++j) u |= (cand[j] == mx) ? (1u << j) : 0u;
      int bpi = __builtin_ctz(u);
      if (lane < CC) bpb[(t0 + q) * CC + lane] = (unsigned char)bpi;
      st = mx + ev[q];
    }
  }
}

// ---------------- backtrace: chunk-composed backpointer maps ----------------
__global__ __launch_bounds__(64) void k_back(const unsigned char* __restrict__ bp,
                                             const int* __restrict__ meta,
                                             float* __restrict__ out_path) {
  __shared__ __align__(16) unsigned char bps[LL * CC];  // 11264 B
  __shared__ unsigned char gs[64 * CC];
  const int b = blockIdx.x, lane = threadIdx.x;
  const int n = meta[b];
  const int bt = meta[BB + b];
  const uint32_t* src = (const uint32_t*)(bp + (size_t)b * LL * CC);
  uint32_t* dst = (uint32_t*)bps;
  for (int i = lane; i < (LL * CC) / 4; i += 64) dst[i] = src[i];
  __syncthreads();
  const int k = lane;
  for (int c = 0; c < CC; ++c) {
    int tag = c;
#pragma unroll
    for (int j = 7; j >= 0; --j) {
      int t = 8 * k + j;
      int nv = bps[t * CC + tag];
      tag = (t < n) ? nv : tag;
    }
    gs[k * CC + c] = (unsigned char)tag;
  }
  __syncthreads();
  int tag = bt, entry = bt;
  for (int kk = 63; kk >= 0; --kk) {
    if (lane == kk) entry = tag;
    tag = gs[kk * CC + tag];
  }
  tag = entry;
  float* op = out_path + (size_t)b * LL;
#pragma unroll
  for (int j = 7; j >= 0; --j) {
    int t = 8 * k + j;
    bool act = t < n;
    op[t] = act ? (float)tag : 0.0f;
    int nv = bps[t * CC + tag];
    tag = act ? nv : tag;
  }
}

extern "C" void kernel_launch(void* const* d_in, const int* in_sizes, int n_in,
                              void* d_out, int out_size, void* d_ws, size_t ws_size,
                              hipStream_t stream) {
  const float* x = (const float*)d_in[0];
  const float* mask = (const float*)d_in[1];
  const float* W = (const float*)d_in[2];
  const float* bias = (const float*)d_in[3];
  const float* trans = (const float*)d_in[4];
  float* out_score = (float*)d_out;                 // [B, C] f32
  float* out_path = (float*)d_out + BB * CC;        // [B, L] as f32 values
  char* ws = (char*)d_ws;
  float* emit = (float*)ws;
  unsigned char* bp = (unsigned char*)(ws + BP_OFF);
  int* meta = (int*)(ws + META_OFF);
  float* pvp = (float*)(ws + PV_OFF);
  float* phi = (float*)(ws + PHI_OFF);

  k_emit<<<dim3((BB * LL) / EROWS), dim3(384), 0, stream>>>(x, W, bias, emit);
  k_seg<<<dim3(NCH, BB), dim3(256), 0, stream>>>(emit, mask, trans, phi);
  k_cmp<<<dim3(BB), dim3(64), 0, stream>>>(phi, mask, trans, out_score, pvp, meta);
  k_rep<<<dim3(NCH, BB), dim3(64), 0, stream>>>(emit, trans, pvp, meta, bp);
  k_back<<<dim3(BB), dim3(64), 0, stream>>>(bp, meta, out_path);
}

// Round 12
// 94.084 us; speedup vs baseline: 1.1243x; 1.1243x over previous
//
#include <hip/hip_runtime.h>
#include <stdint.h>
#include <math.h>

#define CC 22
#define START_I 20
#define STOP_I 21
#define BB 64
#define LL 512
#define DD 512
#define NEGV -100000.0f
#define NCH 32
#define CS 16
#define ER 32  // rows per k_emit block

// ws layout
#define EMIT_FLOATS ((BB * LL + CS) * CC)                // + CS rows slack
#define BP_OFF (((EMIT_FLOATS * 4) + 255) & ~255)
#define BP_BYTES (BB * LL * CC)
#define META_OFF ((BP_OFF + BP_BYTES + 255) & ~255)
#define PV_OFF (META_OFF + 1024)                         // 64*32*22 floats = 180224 B
#define PHI_OFF (PV_OFF + BB * NCH * CC * 4)             // 64*32*22*22 floats = 3.96 MB

// ---------------- emissions GEMM: emit[row][c] = x[row]·W[c] + b[c] ----------------
// thread = (row, k-phase s). k ownership strided: k in {4s+32j}. Per j:
//   x: 8 lanes x 16B = 128B contiguous per row (coalesced)
//   W (LDS, stride 516): banks 4(c+s)%32 -> all 32 banks once = conflict-free
//   88 FMA on 22 independent acc chains.
// 8-phase partials tree-reduced via shfl_xor (fp32 reorder ~1e-3 << threshold).
__global__ __launch_bounds__(256) void k_emit(const float* __restrict__ x,
                                              const float* __restrict__ W,
                                              const float* __restrict__ bias,
                                              float* __restrict__ emit) {
  __shared__ float Wl[CC * 516 + 4];  // 45.4 KB -> 3 blocks/CU, 12 waves/CU
  const int tid = threadIdx.x;
#pragma unroll
  for (int it = 0; it < 11; ++it) {  // stage W coalesced: 2816 float4
    int g = it * 256 + tid;
    if (g < CC * (DD / 4)) {
      int c = g >> 7, d4 = g & 127;
      *(float4*)(Wl + c * 516 + 4 * d4) = ((const float4*)W)[g];
    }
  }
  __syncthreads();
  const int s = tid & 7;    // k-phase
  const int rl = tid >> 3;  // row_local 0..31
  const size_t row = (size_t)blockIdx.x * ER + rl;
  const float* xr = x + row * DD + 4 * s;
  const float* wb = Wl + 4 * s;
  float acc[CC];
#pragma unroll
  for (int c = 0; c < CC; ++c) acc[c] = 0.f;
#pragma unroll
  for (int j = 0; j < 16; ++j) {
    float4 xv = *(const float4*)(xr + 32 * j);
#pragma unroll
    for (int c = 0; c < CC; ++c) {
      float4 wv = *(const float4*)(wb + 516 * c + 32 * j);
      acc[c] += xv.x * wv.x + xv.y * wv.y + xv.z * wv.z + xv.w * wv.w;
    }
  }
  // reduce the 8 k-phases (lane bits 0..2), balanced tree
#pragma unroll
  for (int c = 0; c < CC; ++c) {
    acc[c] += __shfl_xor(acc[c], 1);
    acc[c] += __shfl_xor(acc[c], 2);
    acc[c] += __shfl_xor(acc[c], 4);
  }
  if (s == 0) {
#pragma unroll
    for (int c = 0; c < CC; ++c) emit[row * CC + c] = acc[c] + bias[c];
  }
}

__device__ __forceinline__ float rlf(float v, int l) {
  return __int_as_float(__builtin_amdgcn_readlane(__float_as_int(v), l));
}

// ---------------- segment transfer matrices (parallel-in-time Viterbi) ----------
__global__ __launch_bounds__(256) void k_seg(const float* __restrict__ emit,
                                             const float* __restrict__ mask,
                                             const float* __restrict__ trans,
                                             float* __restrict__ phi) {
  __shared__ float Ph[2][CC][23];
  __shared__ float els[CS * CC];
  const int seg = blockIdx.x, b = blockIdx.y;
  const int tid = threadIdx.x;
  const int lane = tid & 63;
  int n = 0;  // each wave computes redundantly (no sync needed)
#pragma unroll
  for (int k = 0; k < 8; ++k)
    n += __popcll(__ballot(mask[(size_t)b * LL + k * 64 + lane] > 0.0f));
  const int t0 = seg * CS;
  for (int i = tid; i < CS * CC; i += 256)  // full 352-entry fill
    els[i] = emit[((size_t)b * LL + t0) * CC + i];
  const bool own = tid < 242;
  const int to2 = own ? tid / CC : 0;   // 0..10
  const int frm0 = own ? tid % CC : 0;  // 0..21
  float T0[CC], T1[CC];
  if (own) {
#pragma unroll
    for (int f = 0; f < CC; ++f) {
      T0[f] = trans[to2 * CC + f];
      T1[f] = trans[(to2 + 11) * CC + f];
    }
    Ph[0][to2][frm0] = (to2 == frm0) ? 0.0f : -INFINITY;
    Ph[0][to2 + 11][frm0] = (to2 + 11 == frm0) ? 0.0f : -INFINITY;
  }
  __syncthreads();
  int steps = n - t0;
  steps = steps < 0 ? 0 : (steps > CS ? CS : steps);
  int c = 0;
  for (int q = 0; q < steps; ++q) {  // block-uniform trip count
    if (own) {
      float a0 = -INFINITY, a1 = -INFINITY;
#pragma unroll
      for (int f = 0; f < CC; ++f) {
        float v = Ph[c][f][frm0];
        a0 = fmaxf(a0, v + T0[f]);
        a1 = fmaxf(a1, v + T1[f]);
      }
      Ph[c ^ 1][to2][frm0] = a0 + els[q * CC + to2];
      Ph[c ^ 1][to2 + 11][frm0] = a1 + els[q * CC + to2 + 11];
    }
    __syncthreads();
    c ^= 1;
  }
  if (own) {
    float* pb = phi + ((size_t)b * NCH + seg) * CC * CC;
    pb[to2 * CC + frm0] = Ph[c][to2][frm0];
    pb[(to2 + 11) * CC + frm0] = Ph[c][to2 + 11][frm0];
  }
}

// ---------------- compose: 32 matrix-vector max-plus steps per batch ----------
__global__ __launch_bounds__(64) void k_cmp(const float* __restrict__ phi,
                                            const float* __restrict__ mask,
                                            const float* __restrict__ trans,
                                            float* __restrict__ out_score,
                                            float* __restrict__ pv,
                                            int* __restrict__ meta) {
  const int b = blockIdx.x;
  const int lane = threadIdx.x;
  const int lc = lane < CC ? lane : CC - 1;
  const float Tstop = trans[STOP_I * CC + lc];
  int n = 0;
#pragma unroll
  for (int k = 0; k < 8; ++k)
    n += __popcll(__ballot(mask[(size_t)b * LL + k * 64 + lane] > 0.0f));

  float st = (lane == START_I) ? 0.0f : NEGV;
  const float* pb = phi + (size_t)b * NCH * CC * CC;
  float row[CC], nrow[CC];
#pragma unroll
  for (int f = 0; f < CC; ++f) row[f] = pb[lc * CC + f];
  for (int s = 0; s < NCH; ++s) {
    if (lane < CC) pv[((size_t)b * NCH + s) * CC + lane] = st;
    if (s + 1 < NCH) {
#pragma unroll
      for (int f = 0; f < CC; ++f) nrow[f] = pb[((s + 1) * CC + lc) * CC + f];
    }
    float a = -INFINITY;
#pragma unroll
    for (int f = 0; f < CC; ++f) a = fmaxf(a, row[f] + rlf(st, f));
    st = a;  // identity segments preserve st exactly
#pragma unroll
    for (int f = 0; f < CC; ++f) row[f] = nrow[f];
  }

  float fin = st + Tstop;
  if (lane < CC) out_score[b * CC + lane] = fin;
  float bv = -3.0e38f;
  int bt = 0;
#pragma unroll
  for (int k = 0; k < CC; ++k) {
    float v = rlf(fin, k);
    bool g = v > bv;
    bv = g ? v : bv;
    bt = g ? k : bt;
  }
  if (lane == 0) { meta[b] = n; meta[BB + b] = bt; }
}

// ---------------- parallel replay: backpointers from checkpoints ----------------
__global__ __launch_bounds__(64) void k_rep(const float* __restrict__ emit,
                                            const float* __restrict__ trans,
                                            const float* __restrict__ pv,
                                            const int* __restrict__ meta,
                                            unsigned char* __restrict__ bp) {
  const int c = blockIdx.x, b = blockIdx.y;
  const int lane = threadIdx.x;
  const int n = meta[b];
  const int t0 = c * CS;
  if (t0 >= n) return;
  const int lc = lane < CC ? lane : CC - 1;
  float Trow[CC];
#pragma unroll
  for (int j = 0; j < CC; ++j) Trow[j] = trans[lc * CC + j];
  float st = pv[((size_t)b * NCH + c) * CC + lc];
  const float* eb = emit + (size_t)b * LL * CC;
  float ev[CS];
#pragma unroll
  for (int q = 0; q < CS; ++q) {
    ev[q] = eb[(t0 + q) * CC + lc];
    asm volatile("" : "+v"(ev[q]));
  }
  unsigned char* bpb = bp + (size_t)b * LL * CC;
  const int m = (n - t0) < CS ? (n - t0) : CS;
#pragma unroll
  for (int q = 0; q < CS; ++q) {
    if (q < m) {
      float cand[CC];
#pragma unroll
      for (int j = 0; j < CC; ++j) cand[j] = rlf(st, j) + Trow[j];
      float m0 = fmaxf(fmaxf(cand[0], cand[1]), cand[2]);
      float m1 = fmaxf(fmaxf(cand[3], cand[4]), cand[5]);
      float m2 = fmaxf(fmaxf(cand[6], cand[7]), cand[8]);
      float m3 = fmaxf(fmaxf(cand[9], cand[10]), cand[11]);
      float m4 = fmaxf(fmaxf(cand[12], cand[13]), cand[14]);
      float m5 = fmaxf(fmaxf(cand[15], cand[16]), cand[17]);
      float m6 = fmaxf(fmaxf(cand[18], cand[19]), cand[20]);
      float n0 = fmaxf(fmaxf(m0, m1), m2);
      float n1 = fmaxf(fmaxf(m3, m4), m5);
      float n2 = fmaxf(m6, cand[21]);
      float mx = fmaxf(fmaxf(n0, n1), n2);
      unsigned u = 0;
#pragma unroll
      for (int j = 0; j < CC; ++j) u |= (cand[j] == mx) ? (1u << j) : 0u;
      int bpi = __builtin_ctz(u);
      if (lane < CC) bpb[(t0 + q) * CC + lane] = (unsigned char)bpi;
      st = mx + ev[q];
    }
  }
}

// ---------------- backtrace: chunk-composed backpointer maps ----------------
__global__ __launch_bounds__(64) void k_back(const unsigned char* __restrict__ bp,
                                             const int* __restrict__ meta,
                                             float* __restrict__ out_path) {
  __shared__ __align__(16) unsigned char bps[LL * CC];  // 11264 B
  __shared__ unsigned char gs[64 * CC];
  const int b = blockIdx.x, lane = threadIdx.x;
  const int n = meta[b];
  const int bt = meta[BB + b];
  const uint32_t* src = (const uint32_t*)(bp + (size_t)b * LL * CC);
  uint32_t* dst = (uint32_t*)bps;
  for (int i = lane; i < (LL * CC) / 4; i += 64) dst[i] = src[i];
  __syncthreads();
  const int k = lane;
  for (int c = 0; c < CC; ++c) {
    int tag = c;
#pragma unroll
    for (int j = 7; j >= 0; --j) {
      int t = 8 * k + j;
      int nv = bps[t * CC + tag];
      tag = (t < n) ? nv : tag;
    }
    gs[k * CC + c] = (unsigned char)tag;
  }
  __syncthreads();
  int tag = bt, entry = bt;
  for (int kk = 63; kk >= 0; --kk) {
    if (lane == kk) entry = tag;
    tag = gs[kk * CC + tag];
  }
  tag = entry;
  float* op = out_path + (size_t)b * LL;
#pragma unroll
  for (int j = 7; j >= 0; --j) {
    int t = 8 * k + j;
    bool act = t < n;
    op[t] = act ? (float)tag : 0.0f;
    int nv = bps[t * CC + tag];
    tag = act ? nv : tag;
  }
}

extern "C" void kernel_launch(void* const* d_in, const int* in_sizes, int n_in,
                              void* d_out, int out_size, void* d_ws, size_t ws_size,
                              hipStream_t stream) {
  const float* x = (const float*)d_in[0];
  const float* mask = (const float*)d_in[1];
  const float* W = (const float*)d_in[2];
  const float* bias = (const float*)d_in[3];
  const float* trans = (const float*)d_in[4];
  float* out_score = (float*)d_out;                 // [B, C] f32
  float* out_path = (float*)d_out + BB * CC;        // [B, L] as f32 values
  char* ws = (char*)d_ws;
  float* emit = (float*)ws;
  unsigned char* bp = (unsigned char*)(ws + BP_OFF);
  int* meta = (int*)(ws + META_OFF);
  float* pvp = (float*)(ws + PV_OFF);
  float* phi = (float*)(ws + PHI_OFF);

  k_emit<<<dim3((BB * LL) / ER), dim3(256), 0, stream>>>(x, W, bias, emit);
  k_seg<<<dim3(NCH, BB), dim3(256), 0, stream>>>(emit, mask, trans, phi);
  k_cmp<<<dim3(BB), dim3(64), 0, stream>>>(phi, mask, trans, out_score, pvp, meta);
  k_rep<<<dim3(NCH, BB), dim3(64), 0, stream>>>(emit, trans, pvp, meta, bp);
  k_back<<<dim3(BB), dim3(64), 0, stream>>>(bp, meta, out_path);
}

// Round 13
// 78.066 us; speedup vs baseline: 1.3550x; 1.2052x over previous
//
#include <hip/hip_runtime.h>
#include <stdint.h>
#include <math.h>

#define CC 22
#define START_I 20
#define STOP_I 21
#define BB 64
#define LL 512
#define DD 512
#define NEGV -100000.0f
#define NCH 32
#define CS 16
#define BMR 64   // rows per k_emit block
#define KT 128   // k-chunk
#define ALD 136  // A lds row stride (bf16): 272B = 17*16 -> conflict-free b128
#define WLD 520  // W lds row stride (bf16): 1040B = 65*16 -> conflict-free b128

// ws layout
#define EMIT_FLOATS ((BB * LL + CS) * CC)                // + CS rows slack
#define BP_OFF (((EMIT_FLOATS * 4) + 255) & ~255)
#define BP_BYTES (BB * LL * CC)
#define META_OFF ((BP_OFF + BP_BYTES + 255) & ~255)
#define PV_OFF (META_OFF + 1024)                         // 64*32*22 floats = 180224 B
#define PHI_OFF (PV_OFF + BB * NCH * CC * 4)             // 64*32*22*22 floats = 3.96 MB

typedef __attribute__((ext_vector_type(8))) short bf16x8;
typedef __attribute__((ext_vector_type(4))) float f32x4;

__device__ __forceinline__ unsigned short f2bf(float f) {  // RTNE f32->bf16
  unsigned u = __float_as_uint(f);
  return (unsigned short)((u + 0x7fffu + ((u >> 16) & 1u)) >> 16);
}

// ---------------- emissions GEMM via bf16 MFMA ----------------
// emit[row][c] = x[row]·W[c] + b[c].  M=32768, N=22 (padded 32), K=512.
// Block: 64 rows, 4 waves; wave = 16 rows x 32 cols; K in 4 chunks of 128,
// A double-buffered in LDS (global f32 -> bf16 fused into coalesced staging).
// D-mapping (verified guide): col=lane&15 <- arg1(W), row=(lane>>4)*4+reg <- arg0(x).
__global__ __launch_bounds__(256) void k_emit(const float* __restrict__ x,
                                              const float* __restrict__ W,
                                              const float* __restrict__ bias,
                                              float* __restrict__ emit) {
  __shared__ unsigned short Wl[32 * WLD];      // 33,280 B
  __shared__ unsigned short Al[2][BMR * ALD];  // 2 x 17,408 B (total ~68 KB)
  const int tid = threadIdx.x;
  const size_t rowbase = (size_t)blockIdx.x * BMR;

  // stage W whole (classes 22..31 zero-padded)
  for (int g = tid; g < 32 * 512; g += 256) {
    int c = g >> 9, k = g & 511;
    float v = (c < CC) ? W[c * 512 + k] : 0.0f;
    Wl[c * WLD + k] = f2bf(v);
  }
  // stage A chunk 0: thread t -> (kq = t&31 float4-col, r8 = t>>5), 8 rows/pass
  const int kq = tid & 31, r8 = tid >> 5;
#pragma unroll
  for (int p = 0; p < 8; ++p) {
    int r = r8 + 8 * p;
    float4 v = *(const float4*)(x + (rowbase + r) * DD + 4 * kq);
    ushort4 pk = make_ushort4(f2bf(v.x), f2bf(v.y), f2bf(v.z), f2bf(v.w));
    *(ushort4*)&Al[0][r * ALD + 4 * kq] = pk;
  }

  const int lane = tid & 63;
  const int wrow0 = (tid >> 6) * 16;  // wave's 16-row tile
  const int am = lane & 15;           // M/N index within fragment
  const int ag = lane >> 4;           // k-group (8 bf16 each)
  f32x4 acc0 = {0.f, 0.f, 0.f, 0.f};
  f32x4 acc1 = {0.f, 0.f, 0.f, 0.f};

  int buf = 0;
  for (int kc = 0; kc < 4; ++kc) {
    __syncthreads();  // Al[buf] (and Wl on first iter) ready
    if (kc < 3) {
#pragma unroll
      for (int p = 0; p < 8; ++p) {
        int r = r8 + 8 * p;
        float4 v = *(const float4*)(x + (rowbase + r) * DD + (kc + 1) * KT + 4 * kq);
        ushort4 pk = make_ushort4(f2bf(v.x), f2bf(v.y), f2bf(v.z), f2bf(v.w));
        *(ushort4*)&Al[buf ^ 1][r * ALD + 4 * kq] = pk;
      }
    }
#pragma unroll
    for (int s = 0; s < 4; ++s) {
      bf16x8 a = *(const bf16x8*)&Al[buf][(wrow0 + am) * ALD + s * 32 + ag * 8];
      bf16x8 b0 = *(const bf16x8*)&Wl[am * WLD + kc * KT + s * 32 + ag * 8];
      bf16x8 b1 = *(const bf16x8*)&Wl[(am + 16) * WLD + kc * KT + s * 32 + ag * 8];
      acc0 = __builtin_amdgcn_mfma_f32_16x16x32_bf16(a, b0, acc0, 0, 0, 0);
      acc1 = __builtin_amdgcn_mfma_f32_16x16x32_bf16(a, b1, acc1, 0, 0, 0);
    }
    buf ^= 1;
  }

  // epilogue: col = am (tile0) / am+16 (tile1), row = wrow0 + 4*ag + reg
  const float bc0 = bias[am];
  const float bc1 = (am < 6) ? bias[am + 16] : 0.0f;
#pragma unroll
  for (int reg = 0; reg < 4; ++reg) {
    size_t row = rowbase + wrow0 + 4 * ag + reg;
    emit[row * CC + am] = acc0[reg] + bc0;
    if (am < 6) emit[row * CC + am + 16] = acc1[reg] + bc1;
  }
}

__device__ __forceinline__ float rlf(float v, int l) {
  return __int_as_float(__builtin_amdgcn_readlane(__float_as_int(v), l));
}

// ---------------- segment transfer matrices (parallel-in-time Viterbi) ----------
__global__ __launch_bounds__(256) void k_seg(const float* __restrict__ emit,
                                             const float* __restrict__ mask,
                                             const float* __restrict__ trans,
                                             float* __restrict__ phi) {
  __shared__ float Ph[2][CC][23];
  __shared__ float els[CS * CC];
  const int seg = blockIdx.x, b = blockIdx.y;
  const int tid = threadIdx.x;
  const int lane = tid & 63;
  int n = 0;  // each wave computes redundantly (no sync needed)
#pragma unroll
  for (int k = 0; k < 8; ++k)
    n += __popcll(__ballot(mask[(size_t)b * LL + k * 64 + lane] > 0.0f));
  const int t0 = seg * CS;
  for (int i = tid; i < CS * CC; i += 256)  // full 352-entry fill
    els[i] = emit[((size_t)b * LL + t0) * CC + i];
  const bool own = tid < 242;
  const int to2 = own ? tid / CC : 0;   // 0..10
  const int frm0 = own ? tid % CC : 0;  // 0..21
  float T0[CC], T1[CC];
  if (own) {
#pragma unroll
    for (int f = 0; f < CC; ++f) {
      T0[f] = trans[to2 * CC + f];
      T1[f] = trans[(to2 + 11) * CC + f];
    }
    Ph[0][to2][frm0] = (to2 == frm0) ? 0.0f : -INFINITY;
    Ph[0][to2 + 11][frm0] = (to2 + 11 == frm0) ? 0.0f : -INFINITY;
  }
  __syncthreads();
  int steps = n - t0;
  steps = steps < 0 ? 0 : (steps > CS ? CS : steps);
  int c = 0;
  for (int q = 0; q < steps; ++q) {  // block-uniform trip count
    if (own) {
      float a0 = -INFINITY, a1 = -INFINITY;
#pragma unroll
      for (int f = 0; f < CC; ++f) {
        float v = Ph[c][f][frm0];
        a0 = fmaxf(a0, v + T0[f]);
        a1 = fmaxf(a1, v + T1[f]);
      }
      Ph[c ^ 1][to2][frm0] = a0 + els[q * CC + to2];
      Ph[c ^ 1][to2 + 11][frm0] = a1 + els[q * CC + to2 + 11];
    }
    __syncthreads();
    c ^= 1;
  }
  if (own) {
    float* pb = phi + ((size_t)b * NCH + seg) * CC * CC;
    pb[to2 * CC + frm0] = Ph[c][to2][frm0];
    pb[(to2 + 11) * CC + frm0] = Ph[c][to2 + 11][frm0];
  }
}

// ---------------- compose: 32 matrix-vector max-plus steps per batch ----------
__global__ __launch_bounds__(64) void k_cmp(const float* __restrict__ phi,
                                            const float* __restrict__ mask,
                                            const float* __restrict__ trans,
                                            float* __restrict__ out_score,
                                            float* __restrict__ pv,
                                            int* __restrict__ meta) {
  const int b = blockIdx.x;
  const int lane = threadIdx.x;
  const int lc = lane < CC ? lane : CC - 1;
  const float Tstop = trans[STOP_I * CC + lc];
  int n = 0;
#pragma unroll
  for (int k = 0; k < 8; ++k)
    n += __popcll(__ballot(mask[(size_t)b * LL + k * 64 + lane] > 0.0f));

  float st = (lane == START_I) ? 0.0f : NEGV;
  const float* pb = phi + (size_t)b * NCH * CC * CC;
  float row[CC], nrow[CC];
#pragma unroll
  for (int f = 0; f < CC; ++f) row[f] = pb[lc * CC + f];
  for (int s = 0; s < NCH; ++s) {
    if (lane < CC) pv[((size_t)b * NCH + s) * CC + lane] = st;
    if (s + 1 < NCH) {
#pragma unroll
      for (int f = 0; f < CC; ++f) nrow[f] = pb[((s + 1) * CC + lc) * CC + f];
    }
    float a = -INFINITY;
#pragma unroll
    for (int f = 0; f < CC; ++f) a = fmaxf(a, row[f] + rlf(st, f));
    st = a;  // identity segments preserve st exactly
#pragma unroll
    for (int f = 0; f < CC; ++f) row[f] = nrow[f];
  }

  float fin = st + Tstop;
  if (lane < CC) out_score[b * CC + lane] = fin;
  float bv = -3.0e38f;
  int bt = 0;
#pragma unroll
  for (int k = 0; k < CC; ++k) {
    float v = rlf(fin, k);
    bool g = v > bv;
    bv = g ? v : bv;
    bt = g ? k : bt;
  }
  if (lane == 0) { meta[b] = n; meta[BB + b] = bt; }
}

// ---------------- parallel replay: backpointers from checkpoints ----------------
__global__ __launch_bounds__(64) void k_rep(const float* __restrict__ emit,
                                            const float* __restrict__ trans,
                                            const float* __restrict__ pv,
                                            const int* __restrict__ meta,
                                            unsigned char* __restrict__ bp) {
  const int c = blockIdx.x, b = blockIdx.y;
  const int lane = threadIdx.x;
  const int n = meta[b];
  const int t0 = c * CS;
  if (t0 >= n) return;
  const int lc = lane < CC ? lane : CC - 1;
  float Trow[CC];
#pragma unroll
  for (int j = 0; j < CC; ++j) Trow[j] = trans[lc * CC + j];
  float st = pv[((size_t)b * NCH + c) * CC + lc];
  const float* eb = emit + (size_t)b * LL * CC;
  float ev[CS];
#pragma unroll
  for (int q = 0; q < CS; ++q) {
    ev[q] = eb[(t0 + q) * CC + lc];
    asm volatile("" : "+v"(ev[q]));
  }
  unsigned char* bpb = bp + (size_t)b * LL * CC;
  const int m = (n - t0) < CS ? (n - t0) : CS;
#pragma unroll
  for (int q = 0; q < CS; ++q) {
    if (q < m) {
      float cand[CC];
#pragma unroll
      for (int j = 0; j < CC; ++j) cand[j] = rlf(st, j) + Trow[j];
      float m0 = fmaxf(fmaxf(cand[0], cand[1]), cand[2]);
      float m1 = fmaxf(fmaxf(cand[3], cand[4]), cand[5]);
      float m2 = fmaxf(fmaxf(cand[6], cand[7]), cand[8]);
      float m3 = fmaxf(fmaxf(cand[9], cand[10]), cand[11]);
      float m4 = fmaxf(fmaxf(cand[12], cand[13]), cand[14]);
      float m5 = fmaxf(fmaxf(cand[15], cand[16]), cand[17]);
      float m6 = fmaxf(fmaxf(cand[18], cand[19]), cand[20]);
      float n0 = fmaxf(fmaxf(m0, m1), m2);
      float n1 = fmaxf(fmaxf(m3, m4), m5);
      float n2 = fmaxf(m6, cand[21]);
      float mx = fmaxf(fmaxf(n0, n1), n2);
      unsigned u = 0;
#pragma unroll
      for (int j = 0; j < CC; ++j) u |= (cand[j] == mx) ? (1u << j) : 0u;
      int bpi = __builtin_ctz(u);
      if (lane < CC) bpb[(t0 + q) * CC + lane] = (unsigned char)bpi;
      st = mx + ev[q];
    }
  }
}

// ---------------- backtrace: chunk-composed backpointer maps ----------------
__global__ __launch_bounds__(64) void k_back(const unsigned char* __restrict__ bp,
                                             const int* __restrict__ meta,
                                             float* __restrict__ out_path) {
  __shared__ __align__(16) unsigned char bps[LL * CC];  // 11264 B
  __shared__ unsigned char gs[64 * CC];
  const int b = blockIdx.x, lane = threadIdx.x;
  const int n = meta[b];
  const int bt = meta[BB + b];
  const uint32_t* src = (const uint32_t*)(bp + (size_t)b * LL * CC);
  uint32_t* dst = (uint32_t*)bps;
  for (int i = lane; i < (LL * CC) / 4; i += 64) dst[i] = src[i];
  __syncthreads();
  const int k = lane;
  for (int c = 0; c < CC; ++c) {
    int tag = c;
#pragma unroll
    for (int j = 7; j >= 0; --j) {
      int t = 8 * k + j;
      int nv = bps[t * CC + tag];
      tag = (t < n) ? nv : tag;
    }
    gs[k * CC + c] = (unsigned char)tag;
  }
  __syncthreads();
  int tag = bt, entry = bt;
  for (int kk = 63; kk >= 0; --kk) {
    if (lane == kk) entry = tag;
    tag = gs[kk * CC + tag];
  }
  tag = entry;
  float* op = out_path + (size_t)b * LL;
#pragma unroll
  for (int j = 7; j >= 0; --j) {
    int t = 8 * k + j;
    bool act = t < n;
    op[t] = act ? (float)tag : 0.0f;
    int nv = bps[t * CC + tag];
    tag = act ? nv : tag;
  }
}

extern "C" void kernel_launch(void* const* d_in, const int* in_sizes, int n_in,
                              void* d_out, int out_size, void* d_ws, size_t ws_size,
                              hipStream_t stream) {
  const float* x = (const float*)d_in[0];
  const float* mask = (const float*)d_in[1];
  const float* W = (const float*)d_in[2];
  const float* bias = (const float*)d_in[3];
  const float* trans = (const float*)d_in[4];
  float* out_score = (float*)d_out;                 // [B, C] f32
  float* out_path = (float*)d_out + BB * CC;        // [B, L] as f32 values
  char* ws = (char*)d_ws;
  float* emit = (float*)ws;
  unsigned char* bp = (unsigned char*)(ws + BP_OFF);
  int* meta = (int*)(ws + META_OFF);
  float* pvp = (float*)(ws + PV_OFF);
  float* phi = (float*)(ws + PHI_OFF);

  k_emit<<<dim3((BB * LL) / BMR), dim3(256), 0, stream>>>(x, W, bias, emit);
  k_seg<<<dim3(NCH, BB), dim3(256), 0, stream>>>(emit, mask, trans, phi);
  k_cmp<<<dim3(BB), dim3(64), 0, stream>>>(phi, mask, trans, out_score, pvp, meta);
  k_rep<<<dim3(NCH, BB), dim3(64), 0, stream>>>(emit, trans, pvp, meta, bp);
  k_back<<<dim3(BB), dim3(64), 0, stream>>>(bp, meta, out_path);
}